// Round 4
// baseline (1266.765 us; speedup 1.0000x reference)
//
#include <hip/hip_runtime.h>

// N=65536 vectors (16x4096), D=64, K=1024, all fp32.
// d_out (f32 flat concat): quantized[N*D], one-hot[N*K], loss, cb_loss, commit_loss.
// d_ws unused. The argmin replicates the numpy-f32 reference BIT-EXACTLY:
//   d[n,k] = fl32( fl32(sx[n] + se[k]) - 2*fl32(dot[n,k]) )
// where sx uses numpy pairwise_sum's exact 8-accumulator tree in f32 and
// se/dot are fp64-exact rounded once (their sub-quantum error is irrelevant:
// the final subtraction quantizes to ulp(~64)=7.6e-6). Strict < = np.argmin
// first-index tie-break (exact rounded ties DO occur, ~250/65536 rows).
#define NVEC 65536
#define KCB  1024
#define DIM  64
#define ENC_OFF   ((size_t)NVEC * DIM)            // 4194304
#define LOSS_OFF  (ENC_OFF + (size_t)NVEC * KCB)  // 71303168

__global__ void vq_zero(float* __restrict__ loss3) {
    if (threadIdx.x < 3) loss3[threadIdx.x] = 0.0f;
}

__global__ __launch_bounds__(256) void vq_main(const float* __restrict__ x,
                                               const float* __restrict__ emb,
                                               float* __restrict__ outq,
                                               float* __restrict__ enc,
                                               float* __restrict__ lossacc) {
    __shared__ float se[KCB];   // fl32(||e_k||^2), fp64-exact then rounded
    __shared__ int sidx[256];
    __shared__ float red[4];

    // Phase 0: block-local codebook norms (4 codes/thread).
    for (int k = threadIdx.x; k < KCB; k += 256) {
        const float4* er = (const float4*)(emb + (size_t)k * DIM);
        double s0 = 0.0, s1 = 0.0, s2 = 0.0, s3 = 0.0;
#pragma unroll
        for (int i = 0; i < 16; i++) {
            float4 e = er[i];
            s0 = fma((double)e.x, (double)e.x, s0);
            s1 = fma((double)e.y, (double)e.y, s1);
            s2 = fma((double)e.z, (double)e.z, s2);
            s3 = fma((double)e.w, (double)e.w, s3);
        }
        se[k] = (float)((s0 + s1) + (s2 + s3));
    }
    __syncthreads();

    const int n = blockIdx.x * 256 + threadIdx.x;
    const float4* xr = (const float4*)(x + (size_t)n * DIM);
    float xf[64];
#pragma unroll
    for (int i = 0; i < 16; i++) ((float4*)xf)[i] = xr[i];
    double xd[64];
#pragma unroll
    for (int i = 0; i < 64; i++) xd[i] = (double)xf[i];

    // sx = numpy pairwise_sum(fl32(x_i^2), n=64): 8 accumulators, each a
    // sequential f32 chain over stride-8 elements, then the fixed combine
    // tree. __fmul_rn/__fadd_rn block FMA contraction (rounding is the point).
    float r[8];
#pragma unroll
    for (int j = 0; j < 8; j++) r[j] = __fmul_rn(xf[j], xf[j]);
#pragma unroll
    for (int b = 1; b < 8; b++)
#pragma unroll
        for (int j = 0; j < 8; j++)
            r[j] = __fadd_rn(r[j], __fmul_rn(xf[8 * b + j], xf[8 * b + j]));
    float sx = __fadd_rn(
        __fadd_rn(__fadd_rn(r[0], r[1]), __fadd_rn(r[2], r[3])),
        __fadd_rn(__fadd_rn(r[4], r[5]), __fadd_rn(r[6], r[7])));

    float best = 3.4e38f;
    int bidx = 0;
    for (int k = 0; k < KCB; k++) {
        const float4* er = (const float4*)(emb + (size_t)k * DIM);
        double s0 = 0.0, s1 = 0.0, s2 = 0.0, s3 = 0.0;  // fp64 dot, 4 chains
#pragma unroll
        for (int i = 0; i < 16; i++) {
            float4 e = er[i];
            s0 = fma((double)e.x, xd[4 * i + 0], s0);
            s1 = fma((double)e.y, xd[4 * i + 1], s1);
            s2 = fma((double)e.z, xd[4 * i + 2], s2);
            s3 = fma((double)e.w, xd[4 * i + 3], s3);
        }
        float dot32 = (float)((s0 + s1) + (s2 + s3));
        float t1 = __fadd_rn(sx, se[k]);                       // fl32(sx+se)
        float d = __fsub_rn(t1, __fmul_rn(2.0f, dot32));       // fl32(t1-2dot)
        if (d < best) { best = d; bidx = k; }  // strict < == first-index tie
    }

    sidx[threadIdx.x] = bidx;

    // quantized out = emb[bidx]; accumulate sum((e-x)^2) for the losses
    const float4* eb = (const float4*)(emb + (size_t)bidx * DIM);
    float4* oq = (float4*)(outq + (size_t)n * DIM);
    float sq = 0.0f;
#pragma unroll
    for (int i = 0; i < 16; i++) {
        float4 e = eb[i];
        float a0 = e.x - xf[4 * i + 0], a1 = e.y - xf[4 * i + 1];
        float a2 = e.z - xf[4 * i + 2], a3 = e.w - xf[4 * i + 3];
        sq += a0 * a0 + a1 * a1 + a2 * a2 + a3 * a3;
        oq[i] = e;
    }
    for (int off = 32; off; off >>= 1) sq += __shfl_down(sq, off);
    int lane = threadIdx.x & 63, w = threadIdx.x >> 6;
    if (lane == 0) red[w] = sq;
    __syncthreads();  // also publishes sidx
    if (threadIdx.x == 0) atomicAdd(lossacc, red[0] + red[1] + red[2] + red[3]);

    // coalesced one-hot slab: 256 rows x 256 float4
    float4* encb = (float4*)enc + (size_t)blockIdx.x * 256 * 256;
    for (int t = threadIdx.x; t < 256 * 256; t += 256) {
        int id = sidx[t >> 8];
        int j = (t & 255) << 2;
        float4 v;
        v.x = (id == j + 0) ? 1.0f : 0.0f;
        v.y = (id == j + 1) ? 1.0f : 0.0f;
        v.z = (id == j + 2) ? 1.0f : 0.0f;
        v.w = (id == j + 3) ? 1.0f : 0.0f;
        encb[t] = v;
    }
}

__global__ void vq_fin(float* __restrict__ loss3) {
    if (threadIdx.x == 0 && blockIdx.x == 0) {
        float m = loss3[1] * (1.0f / (float)((size_t)NVEC * DIM));
        loss3[0] = 1.25f * m;  // loss = cb + 0.25*commit (values identical)
        loss3[1] = m;
        loss3[2] = m;
    }
}

extern "C" void kernel_launch(void* const* d_in, const int* in_sizes, int n_in,
                              void* d_out, int out_size, void* d_ws, size_t ws_size,
                              hipStream_t stream) {
    const float* x = (const float*)d_in[0];    // [16,4096,64] f32
    const float* emb = (const float*)d_in[1];  // [1024,64] f32
    float* out = (float*)d_out;
    (void)d_ws; (void)ws_size;

    hipLaunchKernelGGL(vq_zero, dim3(1), dim3(64), 0, stream, out + LOSS_OFF);
    hipLaunchKernelGGL(vq_main, dim3(NVEC / 256), dim3(256), 0, stream,
                       x, emb, out, out + ENC_OFF, out + LOSS_OFF + 1);
    hipLaunchKernelGGL(vq_fin, dim3(1), dim3(64), 0, stream, out + LOSS_OFF);
}